// Round 1
// baseline (262.699 us; speedup 1.0000x reference)
//
#include <hip/hip_runtime.h>
#include <stdint.h>

typedef __attribute__((ext_vector_type(8))) short bf16x8;
typedef __attribute__((ext_vector_type(4))) float f32x4;

constexpr int NB  = 2;
constexpr int NS  = 2048;
constexpr int NH  = 16;
constexpr int NDH = 64;
constexpr int ND  = 1024;   // NH*NDH

// round-to-nearest-even f32 -> bf16 bits
static __device__ __forceinline__ unsigned short bfbits(float f) {
    union { float f; uint32_t u; } v; v.f = f;
    uint32_t u = v.u + 0x7FFFu + ((v.u >> 16) & 1u);
    return (unsigned short)(u >> 16);
}

static __device__ __forceinline__ void gl_lds16(const void* g, void* l) {
    __builtin_amdgcn_global_load_lds(
        (const __attribute__((address_space(1))) unsigned int*)g,
        (__attribute__((address_space(3))) unsigned int*)l, 16, 0, 0);
}

// ---------------------------------------------------------------------------
// Kernel 1: fused QKV projection.  q[n,j] = sum_d x[n,d]*W[j,d] + b[j]
// grid: (24, 32)  -> blockIdx.x = column tile over [Wq|Wk|Wv] (3*1024/128),
//                    blockIdx.y = token tile (4096/128)
// q,k written [b,h,s,dh]; v written transposed [b,h,dh,s]
// ---------------------------------------------------------------------------
__global__ __launch_bounds__(256, 2)
void qkv_kernel(const float* __restrict__ x,
                const float* __restrict__ Wq, const float* __restrict__ bq,
                const float* __restrict__ Wk, const float* __restrict__ bk,
                const float* __restrict__ Wv, const float* __restrict__ bv,
                unsigned short* __restrict__ qbuf,
                unsigned short* __restrict__ kbuf,
                unsigned short* __restrict__ vtbuf)
{
    __shared__ unsigned short As[128][40];   // stride 80B = 16B-aligned, low-conflict
    __shared__ unsigned short Bs[128][40];

    const int m0  = blockIdx.y * 128;
    const int jg0 = blockIdx.x * 128;        // 0..3071
    const int proj = jg0 >> 10;              // 0=q 1=k 2=v
    const int n0   = jg0 & 1023;
    const float* W    = (proj == 0) ? Wq : (proj == 1) ? Wk : Wv;
    const float* bias = (proj == 0) ? bq : (proj == 1) ? bk : bv;

    const int tid  = threadIdx.x;
    const int lane = tid & 63;
    const int wid  = tid >> 6;
    const int wm = wid >> 1, wn = wid & 1;
    const int l15 = lane & 15, g = lane >> 4;

    const f32x4 fzero = {0.f, 0.f, 0.f, 0.f};
    f32x4 acc[4][4];
#pragma unroll
    for (int i = 0; i < 4; i++)
#pragma unroll
        for (int j = 0; j < 4; j++) acc[i][j] = fzero;

    const int sr = tid >> 3;          // 0..31
    const int sc = (tid & 7) * 4;     // 0..28

    for (int k0 = 0; k0 < 1024; k0 += 32) {
#pragma unroll
        for (int i = 0; i < 4; i++) {
            const int row = i * 32 + sr;
            float4 a4 = *(const float4*)&x[(size_t)(m0 + row) * ND + k0 + sc];
            ushort4 ab = { bfbits(a4.x), bfbits(a4.y), bfbits(a4.z), bfbits(a4.w) };
            *(ushort4*)&As[row][sc] = ab;
            float4 b4 = *(const float4*)&W[(size_t)(n0 + row) * ND + k0 + sc];
            ushort4 bb = { bfbits(b4.x), bfbits(b4.y), bfbits(b4.z), bfbits(b4.w) };
            *(ushort4*)&Bs[row][sc] = bb;
        }
        __syncthreads();
        bf16x8 af[4], bfr[4];
#pragma unroll
        for (int i = 0; i < 4; i++) af[i]  = *(const bf16x8*)&As[wm * 64 + i * 16 + l15][g * 8];
#pragma unroll
        for (int j = 0; j < 4; j++) bfr[j] = *(const bf16x8*)&Bs[wn * 64 + j * 16 + l15][g * 8];
#pragma unroll
        for (int i = 0; i < 4; i++)
#pragma unroll
            for (int j = 0; j < 4; j++)
                acc[i][j] = __builtin_amdgcn_mfma_f32_16x16x32_bf16(af[i], bfr[j], acc[i][j], 0, 0, 0);
        __syncthreads();
    }

    unsigned short* qk_out = (proj == 0) ? qbuf : kbuf;
#pragma unroll
    for (int j = 0; j < 4; j++) {
        const int col = n0 + wn * 64 + j * 16 + l15;     // proj-local 0..1023
        const float bsv = bias[col];
        const int h = col >> 6, dh = col & 63;
#pragma unroll
        for (int i = 0; i < 4; i++) {
#pragma unroll
            for (int r = 0; r < 4; r++) {
                const int row = m0 + wm * 64 + i * 16 + g * 4 + r;   // token 0..4095
                const int b_ = row >> 11, s_ = row & (NS - 1);
                const unsigned short o = bfbits(acc[i][j][r] + bsv);
                if (proj < 2)
                    qk_out[((size_t)((b_ * NH + h) * NS + s_)) * NDH + dh] = o;
                else
                    vtbuf[((size_t)((b_ * NH + h) * NDH + dh)) * NS + s_] = o;
            }
        }
    }
}

// ---------------------------------------------------------------------------
// Kernel 2: flash attention.  grid (16, 32): x = q-tile (128 rows), y = (b,h)
// 512 threads = 8 waves, 16 q-rows/wave.  KV tiles of 64, K & V^T staged via
// global_load_lds with XOR-swizzled source so ds_read_b128 frags are ~free.
// ---------------------------------------------------------------------------
__global__ __launch_bounds__(512, 1)
void attn_kernel(const unsigned short* __restrict__ qbuf,
                 const unsigned short* __restrict__ kbuf,
                 const unsigned short* __restrict__ vtbuf,
                 unsigned short* __restrict__ ctxbuf)
{
    __shared__ unsigned short Ks[64 * 64];     // swizzled [t][dh]
    __shared__ unsigned short Vs[64 * 64];     // swizzled [dh][t]
    __shared__ unsigned short Ps[8][16][72];   // per-wave P, stride 144B

    const int bh = blockIdx.y;
    const int q0 = blockIdx.x * 128;
    const int tid  = threadIdx.x;
    const int lane = tid & 63;
    const int wid  = tid >> 6;
    const int l15 = lane & 15, g = lane >> 4;

    const unsigned short* qb = qbuf  + (size_t)bh * NS * NDH;
    const unsigned short* kb = kbuf  + (size_t)bh * NS * NDH;
    const unsigned short* vb = vtbuf + (size_t)bh * NDH * NS;

    // Q fragments (16 rows per wave), hoisted
    const int qrow = q0 + wid * 16 + l15;
    const bf16x8 qf0 = *(const bf16x8*)&qb[(size_t)qrow * NDH + g * 8];
    const bf16x8 qf1 = *(const bf16x8*)&qb[(size_t)qrow * NDH + 32 + g * 8];

    const f32x4 fzero = {0.f, 0.f, 0.f, 0.f};
    f32x4 acc[4];
#pragma unroll
    for (int d = 0; d < 4; d++) acc[d] = fzero;
    float mrow[4] = {-1e30f, -1e30f, -1e30f, -1e30f};
    float lrow[4] = {0.f, 0.f, 0.f, 0.f};

    // staging: LDS linear dest = tid*16, global source pre-swizzled
    const int o    = tid * 16;                       // 0..8191
    const int srow = o >> 7;                         // 0..63
    const int scb  = (o & 127) ^ ((srow & 7) << 4);  // swizzled byte-in-row
    const char* ksrc = (const char*)kb + srow * 128 + scb;
    const char* vsrc = (const char*)vb + (size_t)srow * (NS * 2) + scb;
    char* kdst = (char*)Ks + o;
    char* vdst = (char*)Vs + o;

    const int xm = (l15 & 7) << 4;                   // read-side swizzle
    const char* ksb = (const char*)Ks;
    const char* vsb = (const char*)Vs;

    for (int t = 0; t < NS / 64; t++) {
        gl_lds16(ksrc + (size_t)t * (64 * 128), kdst);
        gl_lds16(vsrc + (size_t)t * 128, vdst);
        __syncthreads();

        // QK^T: 16 q-rows x 64 keys, scaled
        f32x4 sv[4];
#pragma unroll
        for (int kt = 0; kt < 4; kt++) {
            const char* rb = ksb + (kt * 16 + l15) * 128;
            bf16x8 kf0 = *(const bf16x8*)(rb + ((g * 16) ^ xm));
            bf16x8 kf1 = *(const bf16x8*)(rb + ((64 + g * 16) ^ xm));
            f32x4 s4 = fzero;
            s4 = __builtin_amdgcn_mfma_f32_16x16x32_bf16(qf0, kf0, s4, 0, 0, 0);
            s4 = __builtin_amdgcn_mfma_f32_16x16x32_bf16(qf1, kf1, s4, 0, 0, 0);
            sv[kt] = s4 * 0.125f;
        }

        // online softmax (rows live on 16-lane groups; reduce via shfl_xor)
#pragma unroll
        for (int r = 0; r < 4; r++) {
            float mt = fmaxf(fmaxf(sv[0][r], sv[1][r]), fmaxf(sv[2][r], sv[3][r]));
            mt = fmaxf(mt, __shfl_xor(mt, 1));
            mt = fmaxf(mt, __shfl_xor(mt, 2));
            mt = fmaxf(mt, __shfl_xor(mt, 4));
            mt = fmaxf(mt, __shfl_xor(mt, 8));
            const float mn = fmaxf(mrow[r], mt);
            const float alpha = exp2f((mrow[r] - mn) * 1.44269504f);
            mrow[r] = mn;
            lrow[r] *= alpha;
#pragma unroll
            for (int d = 0; d < 4; d++) acc[d][r] *= alpha;
            float psum = 0.f;
#pragma unroll
            for (int kt = 0; kt < 4; kt++) {
                const float p = exp2f((sv[kt][r] - mn) * 1.44269504f);
                psum += p;
                Ps[wid][g * 4 + r][kt * 16 + l15] = bfbits(p);
            }
            psum += __shfl_xor(psum, 1);
            psum += __shfl_xor(psum, 2);
            psum += __shfl_xor(psum, 4);
            psum += __shfl_xor(psum, 8);
            lrow[r] += psum;
        }

        // P (A-frag) from per-wave LDS; V^T (B-frag) from swizzled tile
        const bf16x8 pf0 = *(const bf16x8*)&Ps[wid][l15][g * 8];
        const bf16x8 pf1 = *(const bf16x8*)&Ps[wid][l15][32 + g * 8];
#pragma unroll
        for (int d = 0; d < 4; d++) {
            const char* rb = vsb + (d * 16 + l15) * 128;
            bf16x8 vf0 = *(const bf16x8*)(rb + ((g * 16) ^ xm));
            bf16x8 vf1 = *(const bf16x8*)(rb + ((64 + g * 16) ^ xm));
            acc[d] = __builtin_amdgcn_mfma_f32_16x16x32_bf16(pf0, vf0, acc[d], 0, 0, 0);
            acc[d] = __builtin_amdgcn_mfma_f32_16x16x32_bf16(pf1, vf1, acc[d], 0, 0, 0);
        }
        __syncthreads();
    }

    // epilogue: ctx[b, s, h*64+dh] bf16
    const int b_ = bh >> 4, h_ = bh & 15;
#pragma unroll
    for (int r = 0; r < 4; r++) {
        const float inv = 1.f / lrow[r];
        const int sq = q0 + wid * 16 + g * 4 + r;
        const size_t base = ((size_t)(b_ * NS + sq)) * ND + h_ * NDH;
#pragma unroll
        for (int d = 0; d < 4; d++)
            ctxbuf[base + d * 16 + l15] = bfbits(acc[d][r] * inv);
    }
}

// ---------------------------------------------------------------------------
// Kernel 3: output projection.  out[n,j] = sum_d ctx[n,d]*Wo[j,d] + bo[j], f32
// grid: (8, 32)
// ---------------------------------------------------------------------------
__global__ __launch_bounds__(256, 2)
void out_kernel(const unsigned short* __restrict__ ctx,
                const float* __restrict__ Wo, const float* __restrict__ bo,
                float* __restrict__ out)
{
    __shared__ unsigned short As[128][40];
    __shared__ unsigned short Bs[128][40];

    const int n0 = blockIdx.x * 128;
    const int m0 = blockIdx.y * 128;
    const int tid  = threadIdx.x;
    const int lane = tid & 63;
    const int wid  = tid >> 6;
    const int wm = wid >> 1, wn = wid & 1;
    const int l15 = lane & 15, g = lane >> 4;

    const f32x4 fzero = {0.f, 0.f, 0.f, 0.f};
    f32x4 acc[4][4];
#pragma unroll
    for (int i = 0; i < 4; i++)
#pragma unroll
        for (int j = 0; j < 4; j++) acc[i][j] = fzero;

    const int sr = tid >> 3, sc = (tid & 7) * 4;    // W staging (f32->bf16)
    const int ar = tid >> 2, ac = (tid & 3) * 8;    // ctx staging (bf16 direct)

    for (int k0 = 0; k0 < 1024; k0 += 32) {
#pragma unroll
        for (int i = 0; i < 2; i++) {
            const int row = i * 64 + ar;
            *(uint4*)&As[row][ac] = *(const uint4*)&ctx[(size_t)(m0 + row) * ND + k0 + ac];
        }
#pragma unroll
        for (int i = 0; i < 4; i++) {
            const int row = i * 32 + sr;
            float4 b4 = *(const float4*)&Wo[(size_t)(n0 + row) * ND + k0 + sc];
            ushort4 bb = { bfbits(b4.x), bfbits(b4.y), bfbits(b4.z), bfbits(b4.w) };
            *(ushort4*)&Bs[row][sc] = bb;
        }
        __syncthreads();
        bf16x8 af[4], bfr[4];
#pragma unroll
        for (int i = 0; i < 4; i++) af[i]  = *(const bf16x8*)&As[wm * 64 + i * 16 + l15][g * 8];
#pragma unroll
        for (int j = 0; j < 4; j++) bfr[j] = *(const bf16x8*)&Bs[wn * 64 + j * 16 + l15][g * 8];
#pragma unroll
        for (int i = 0; i < 4; i++)
#pragma unroll
            for (int j = 0; j < 4; j++)
                acc[i][j] = __builtin_amdgcn_mfma_f32_16x16x32_bf16(af[i], bfr[j], acc[i][j], 0, 0, 0);
        __syncthreads();
    }

#pragma unroll
    for (int j = 0; j < 4; j++) {
        const int col = n0 + wn * 64 + j * 16 + l15;
        const float bsv = bo[col];
#pragma unroll
        for (int i = 0; i < 4; i++)
#pragma unroll
            for (int r = 0; r < 4; r++) {
                const int row = m0 + wm * 64 + i * 16 + g * 4 + r;
                out[(size_t)row * ND + col] = acc[i][j][r] + bsv;
            }
    }
}

// ---------------------------------------------------------------------------
extern "C" void kernel_launch(void* const* d_in, const int* in_sizes, int n_in,
                              void* d_out, int out_size, void* d_ws, size_t ws_size,
                              hipStream_t stream) {
    const float* x  = (const float*)d_in[0];
    const float* Wq = (const float*)d_in[1];
    const float* bq = (const float*)d_in[2];
    const float* Wk = (const float*)d_in[3];
    const float* bk = (const float*)d_in[4];
    const float* Wv = (const float*)d_in[5];
    const float* bv = (const float*)d_in[6];
    const float* Wo = (const float*)d_in[7];
    const float* bo = (const float*)d_in[8];
    float* out = (float*)d_out;

    // workspace: q, k, v^T, ctx  (bf16) = 4 * 8.39 MB = 33.6 MB
    const size_t qk_elems = (size_t)NB * NH * NS * NDH;
    unsigned short* qbuf   = (unsigned short*)d_ws;
    unsigned short* kbuf   = qbuf + qk_elems;
    unsigned short* vtbuf  = kbuf + qk_elems;
    unsigned short* ctxbuf = vtbuf + qk_elems;

    qkv_kernel<<<dim3(24, 32), 256, 0, stream>>>(x, Wq, bq, Wk, bk, Wv, bv,
                                                 qbuf, kbuf, vtbuf);
    attn_kernel<<<dim3(16, 32), 512, 0, stream>>>(qbuf, kbuf, vtbuf, ctxbuf);
    out_kernel<<<dim3(8, 32), 256, 0, stream>>>(ctxbuf, Wo, bo, out);
}

// Round 2
// 147.725 us; speedup vs baseline: 1.7783x; 1.7783x over previous
//
#include <hip/hip_runtime.h>
#include <hip/hip_bf16.h>
#include <stdint.h>

typedef __attribute__((ext_vector_type(8))) short bf16x8;
typedef __attribute__((ext_vector_type(8))) unsigned short u16x8;
typedef __attribute__((ext_vector_type(4))) float f32x4;

constexpr int NB  = 2;
constexpr int NS  = 2048;
constexpr int NH  = 16;
constexpr int NDH = 64;
constexpr int ND  = 1024;

static __device__ __forceinline__ unsigned short bfbits(float f) {
    union { float f; uint32_t u; } v; v.f = f;
    uint32_t u = v.u + 0x7FFFu + ((v.u >> 16) & 1u);
    return (unsigned short)(u >> 16);
}

static __device__ __forceinline__ void gl_lds16(const void* g, void* l) {
    __builtin_amdgcn_global_load_lds(
        (const __attribute__((address_space(1))) unsigned int*)g,
        (__attribute__((address_space(3))) unsigned int*)l, 16, 0, 0);
}

// ---------------------------------------------------------------------------
// Kernel 0: f32 -> bf16 convert for x and the 4 weight matrices.
// 2048 elems per block (256 thr x 8). x: 2048 blocks, each W: 512.
// ---------------------------------------------------------------------------
__global__ __launch_bounds__(256)
void cvt_kernel(const float* __restrict__ x,  const float* __restrict__ wq,
                const float* __restrict__ wk, const float* __restrict__ wv,
                const float* __restrict__ wo,
                unsigned short* __restrict__ xb,  unsigned short* __restrict__ wqb,
                unsigned short* __restrict__ wkb, unsigned short* __restrict__ wvb,
                unsigned short* __restrict__ wob)
{
    const int b = blockIdx.x;
    const float* s; unsigned short* d; int off;
    if      (b < 2048) { s = x;  d = xb;  off = b; }
    else if (b < 2560) { s = wq; d = wqb; off = b - 2048; }
    else if (b < 3072) { s = wk; d = wkb; off = b - 2560; }
    else if (b < 3584) { s = wv; d = wvb; off = b - 3072; }
    else               { s = wo; d = wob; off = b - 3584; }
    const size_t idx = ((size_t)off * 256 + threadIdx.x) * 8;
    float4 f0 = *(const float4*)&s[idx];
    float4 f1 = *(const float4*)&s[idx + 4];
    u16x8 o;
    o[0] = bfbits(f0.x); o[1] = bfbits(f0.y); o[2] = bfbits(f0.z); o[3] = bfbits(f0.w);
    o[4] = bfbits(f1.x); o[5] = bfbits(f1.y); o[6] = bfbits(f1.z); o[7] = bfbits(f1.w);
    *(u16x8*)&d[idx] = o;
}

// ---------------------------------------------------------------------------
// Kernel 1: QKV projection, bf16 GEMM (m97 structure): 128x128 tile, BK=64,
// global_load_lds w16 with pre-swizzled source, XOR-swizzled ds_read_b128.
// grid (24, 32).  q written pre-scaled by 0.125; v written transposed.
// ---------------------------------------------------------------------------
__global__ __launch_bounds__(256, 2)
void qkv_kernel(const unsigned short* __restrict__ xb,
                const unsigned short* __restrict__ wqb,
                const unsigned short* __restrict__ wkb,
                const unsigned short* __restrict__ wvb,
                const float* __restrict__ bq, const float* __restrict__ bk,
                const float* __restrict__ bv,
                unsigned short* __restrict__ qbuf,
                unsigned short* __restrict__ kbuf,
                unsigned short* __restrict__ vtbuf)
{
    __shared__ unsigned short As[128 * 64];
    __shared__ unsigned short Bs[128 * 64];

    const int m0  = blockIdx.y * 128;
    const int jg0 = blockIdx.x * 128;
    const int proj = jg0 >> 10;
    const int n0   = jg0 & 1023;
    const unsigned short* W = (proj == 0) ? wqb : (proj == 1) ? wkb : wvb;
    const float* bias       = (proj == 0) ? bq  : (proj == 1) ? bk  : bv;

    const int tid = threadIdx.x, lane = tid & 63, wid = tid >> 6;
    const int wm = wid >> 1, wn = wid & 1;
    const int l15 = lane & 15, g = lane >> 4;

    const f32x4 fzero = {0.f, 0.f, 0.f, 0.f};
    f32x4 acc[4][4];
#pragma unroll
    for (int i = 0; i < 4; i++)
#pragma unroll
        for (int j = 0; j < 4; j++) acc[i][j] = fzero;

    const int srow = tid >> 3;                              // 0..31
    const int scb  = ((tid & 7) * 16) ^ ((srow & 7) << 4);  // pre-swizzled col byte
    const char* asrc = (const char*)xb + (size_t)(m0 + srow) * 2048 + scb;
    const char* bsrc = (const char*)W  + (size_t)(n0 + srow) * 2048 + scb;
    char* adst = (char*)As + tid * 16;
    char* bdst = (char*)Bs + tid * 16;
    const int xm = (l15 & 7) << 4;

    for (int k0 = 0; k0 < 1024; k0 += 64) {
#pragma unroll
        for (int i = 0; i < 4; i++) {
            gl_lds16(asrc + (size_t)i * 32 * 2048 + k0 * 2, adst + i * 4096);
            gl_lds16(bsrc + (size_t)i * 32 * 2048 + k0 * 2, bdst + i * 4096);
        }
        __syncthreads();
#pragma unroll
        for (int kk = 0; kk < 2; kk++) {
            bf16x8 af[4], bfr[4];
#pragma unroll
            for (int i = 0; i < 4; i++) {
                const int row = wm * 64 + i * 16 + l15;
                af[i] = *(const bf16x8*)((const char*)As + row * 128 + ((kk * 64 + g * 16) ^ xm));
            }
#pragma unroll
            for (int j = 0; j < 4; j++) {
                const int row = wn * 64 + j * 16 + l15;
                bfr[j] = *(const bf16x8*)((const char*)Bs + row * 128 + ((kk * 64 + g * 16) ^ xm));
            }
#pragma unroll
            for (int i = 0; i < 4; i++)
#pragma unroll
                for (int j = 0; j < 4; j++)
                    acc[i][j] = __builtin_amdgcn_mfma_f32_16x16x32_bf16(af[i], bfr[j], acc[i][j], 0, 0, 0);
        }
        __syncthreads();
    }

    unsigned short* qk_out = (proj == 0) ? qbuf : kbuf;
    const float qs = (proj == 0) ? 0.125f : 1.0f;    // fold 1/sqrt(64) into q
#pragma unroll
    for (int j = 0; j < 4; j++) {
        const int col = n0 + wn * 64 + j * 16 + l15;
        const float bsv = bias[col];
        const int h = col >> 6, dh = col & 63;
#pragma unroll
        for (int i = 0; i < 4; i++)
#pragma unroll
            for (int r = 0; r < 4; r++) {
                const int row = m0 + wm * 64 + i * 16 + g * 4 + r;
                const int b_ = row >> 11, s_ = row & (NS - 1);
                const unsigned short o = bfbits((acc[i][j][r] + bsv) * qs);
                if (proj < 2)
                    qk_out[((size_t)((b_ * NH + h) * NS + s_)) * NDH + dh] = o;
                else
                    vtbuf[((size_t)((b_ * NH + h) * NDH + dh)) * NS + s_] = o;
            }
    }
}

// ---------------------------------------------------------------------------
// Kernel 2: flash attention, swapped QK^T (lane holds one q-row's scores),
// in-register row softmax + defer-max, K/V double-buffered via counted vmcnt.
// grid (16, 32), 512 threads = 8 waves, 16 q-rows/wave, KVBLK=64.
// ---------------------------------------------------------------------------
__global__ __launch_bounds__(512, 1)
void attn_kernel(const unsigned short* __restrict__ qbuf,
                 const unsigned short* __restrict__ kbuf,
                 const unsigned short* __restrict__ vtbuf,
                 unsigned short* __restrict__ ctxbuf)
{
    __shared__ unsigned short Ks[2][64 * 64];
    __shared__ unsigned short Vs[2][64 * 64];
    __shared__ unsigned short Ps[8][16][72];

    const int bh = blockIdx.y;
    const int q0 = blockIdx.x * 128;
    const int tid = threadIdx.x, lane = tid & 63, wid = tid >> 6;
    const int l15 = lane & 15, g = lane >> 4;
    constexpr float LOG2E = 1.44269504f;

    const unsigned short* qb = qbuf  + (size_t)bh * NS * NDH;
    const unsigned short* kb = kbuf  + (size_t)bh * NS * NDH;
    const unsigned short* vb = vtbuf + (size_t)bh * NDH * NS;

    const int qrow = q0 + wid * 16 + l15;
    const bf16x8 qf0 = *(const bf16x8*)&qb[(size_t)qrow * NDH + g * 8];
    const bf16x8 qf1 = *(const bf16x8*)&qb[(size_t)qrow * NDH + 32 + g * 8];

    const f32x4 fzero = {0.f, 0.f, 0.f, 0.f};
    f32x4 acc[4];
#pragma unroll
    for (int d = 0; d < 4; d++) acc[d] = fzero;
    float m_run = -1e30f, l_run = 0.f;

    const int o = tid * 16;
    const int srow = o >> 7;
    const int scb  = (o & 127) ^ ((srow & 7) << 4);
    const char* ksrc = (const char*)kb + srow * 128 + scb;
    const char* vsrc = (const char*)vb + (size_t)srow * (NS * 2) + scb;
    char* kdst[2] = { (char*)Ks[0] + o, (char*)Ks[1] + o };
    char* vdst[2] = { (char*)Vs[0] + o, (char*)Vs[1] + o };
    const int xm = (l15 & 7) << 4;

    gl_lds16(ksrc, kdst[0]);
    gl_lds16(vsrc, vdst[0]);

    for (int t = 0; t < 32; t++) {
        const int cur = t & 1;
        const int tn  = (t < 31) ? t + 1 : 31;
        gl_lds16(ksrc + (size_t)tn * 8192, kdst[cur ^ 1]);
        gl_lds16(vsrc + (size_t)tn * 128,  vdst[cur ^ 1]);
        asm volatile("s_waitcnt vmcnt(2)" ::: "memory");   // wait tile t only
        __builtin_amdgcn_s_barrier();
        asm volatile("" ::: "memory");

        const char* ksb = (const char*)Ks[cur];
        const char* vsb = (const char*)Vs[cur];

        // swapped QK^T: lane holds S[key = kt*16+g*4+r][qrow = l15]
        f32x4 sv[4];
#pragma unroll
        for (int kt = 0; kt < 4; kt++) {
            const char* rb = ksb + (kt * 16 + l15) * 128;
            bf16x8 kf0 = *(const bf16x8*)(rb + ((g * 16) ^ xm));
            bf16x8 kf1 = *(const bf16x8*)(rb + ((64 + g * 16) ^ xm));
            f32x4 s4 = fzero;
            s4 = __builtin_amdgcn_mfma_f32_16x16x32_bf16(kf0, qf0, s4, 0, 0, 0);
            s4 = __builtin_amdgcn_mfma_f32_16x16x32_bf16(kf1, qf1, s4, 0, 0, 0);
            sv[kt] = s4;
        }

        // row max: in-register over 16 + 2 shuffles across g
        float mt = sv[0][0];
#pragma unroll
        for (int kt = 0; kt < 4; kt++)
#pragma unroll
            for (int r = 0; r < 4; r++) mt = fmaxf(mt, sv[kt][r]);
        mt = fmaxf(mt, __shfl_xor(mt, 16));
        mt = fmaxf(mt, __shfl_xor(mt, 32));

        if (__any(mt > m_run + 8.f)) {                     // defer-max THR=8
            const float mn = fmaxf(m_run, mt);
            const float alpha = exp2f((m_run - mn) * LOG2E);
            m_run = mn;
            l_run *= alpha;
#pragma unroll
            for (int r = 0; r < 4; r++) {
                const float ar = __shfl(alpha, g * 4 + r);
#pragma unroll
                for (int d = 0; d < 4; d++) acc[d][r] *= ar;
            }
        }

        const float mc = m_run * LOG2E;
        float psum = 0.f;
        f32x4 pv[4];
#pragma unroll
        for (int kt = 0; kt < 4; kt++)
#pragma unroll
            for (int r = 0; r < 4; r++) {
                const float p = exp2f(sv[kt][r] * LOG2E - mc);
                pv[kt][r] = p;
                psum += p;
            }
        psum += __shfl_xor(psum, 16);
        psum += __shfl_xor(psum, 32);
        l_run += psum;

        // pack P (RNE via cvt_pk) -> per-wave LDS, b64 writes
#pragma unroll
        for (int kt = 0; kt < 4; kt++) {
            union { __hip_bfloat162 h2[2]; ushort4 u4; } cc;
            float2 lo = { pv[kt][0], pv[kt][1] };
            float2 hi = { pv[kt][2], pv[kt][3] };
            cc.h2[0] = __float22bfloat162_rn(lo);
            cc.h2[1] = __float22bfloat162_rn(hi);
            *(ushort4*)&Ps[wid][l15][kt * 16 + g * 4] = cc.u4;
        }

        const bf16x8 pf0 = *(const bf16x8*)&Ps[wid][l15][g * 8];
        const bf16x8 pf1 = *(const bf16x8*)&Ps[wid][l15][32 + g * 8];
#pragma unroll
        for (int d = 0; d < 4; d++) {
            const char* rb = vsb + (d * 16 + l15) * 128;
            bf16x8 vf0 = *(const bf16x8*)(rb + ((g * 16) ^ xm));
            bf16x8 vf1 = *(const bf16x8*)(rb + ((64 + g * 16) ^ xm));
            acc[d] = __builtin_amdgcn_mfma_f32_16x16x32_bf16(pf0, vf0, acc[d], 0, 0, 0);
            acc[d] = __builtin_amdgcn_mfma_f32_16x16x32_bf16(pf1, vf1, acc[d], 0, 0, 0);
        }
        __builtin_amdgcn_s_barrier();
        asm volatile("" ::: "memory");
    }

    // epilogue: acc rows are q-rows g*4+r; fetch their l via shuffle
    const int b_ = bh >> 4, h_ = bh & 15;
#pragma unroll
    for (int r = 0; r < 4; r++) {
        const float lr  = __shfl(l_run, g * 4 + r);
        const float inv = 1.f / lr;
        const int sq = q0 + wid * 16 + g * 4 + r;
        const size_t base = ((size_t)(b_ * NS + sq)) * ND + h_ * NDH;
#pragma unroll
        for (int d = 0; d < 4; d++)
            ctxbuf[base + d * 16 + l15] = bfbits(acc[d][r] * inv);
    }
}

// ---------------------------------------------------------------------------
// Kernel 3: output projection, same bf16 GEMM structure, f32 epilogue.
// grid (8, 32)
// ---------------------------------------------------------------------------
__global__ __launch_bounds__(256, 2)
void out_kernel(const unsigned short* __restrict__ ctx,
                const unsigned short* __restrict__ wob,
                const float* __restrict__ bo,
                float* __restrict__ out)
{
    __shared__ unsigned short As[128 * 64];
    __shared__ unsigned short Bs[128 * 64];

    const int n0 = blockIdx.x * 128;
    const int m0 = blockIdx.y * 128;
    const int tid = threadIdx.x, lane = tid & 63, wid = tid >> 6;
    const int wm = wid >> 1, wn = wid & 1;
    const int l15 = lane & 15, g = lane >> 4;

    const f32x4 fzero = {0.f, 0.f, 0.f, 0.f};
    f32x4 acc[4][4];
#pragma unroll
    for (int i = 0; i < 4; i++)
#pragma unroll
        for (int j = 0; j < 4; j++) acc[i][j] = fzero;

    const int srow = tid >> 3;
    const int scb  = ((tid & 7) * 16) ^ ((srow & 7) << 4);
    const char* asrc = (const char*)ctx + (size_t)(m0 + srow) * 2048 + scb;
    const char* bsrc = (const char*)wob + (size_t)(n0 + srow) * 2048 + scb;
    char* adst = (char*)As + tid * 16;
    char* bdst = (char*)Bs + tid * 16;
    const int xm = (l15 & 7) << 4;

    for (int k0 = 0; k0 < 1024; k0 += 64) {
#pragma unroll
        for (int i = 0; i < 4; i++) {
            gl_lds16(asrc + (size_t)i * 32 * 2048 + k0 * 2, adst + i * 4096);
            gl_lds16(bsrc + (size_t)i * 32 * 2048 + k0 * 2, bdst + i * 4096);
        }
        __syncthreads();
#pragma unroll
        for (int kk = 0; kk < 2; kk++) {
            bf16x8 af[4], bfr[4];
#pragma unroll
            for (int i = 0; i < 4; i++) {
                const int row = wm * 64 + i * 16 + l15;
                af[i] = *(const bf16x8*)((const char*)As + row * 128 + ((kk * 64 + g * 16) ^ xm));
            }
#pragma unroll
            for (int j = 0; j < 4; j++) {
                const int row = wn * 64 + j * 16 + l15;
                bfr[j] = *(const bf16x8*)((const char*)Bs + row * 128 + ((kk * 64 + g * 16) ^ xm));
            }
#pragma unroll
            for (int i = 0; i < 4; i++)
#pragma unroll
                for (int j = 0; j < 4; j++)
                    acc[i][j] = __builtin_amdgcn_mfma_f32_16x16x32_bf16(af[i], bfr[j], acc[i][j], 0, 0, 0);
        }
        __syncthreads();
    }

#pragma unroll
    for (int j = 0; j < 4; j++) {
        const int col = n0 + wn * 64 + j * 16 + l15;
        const float bsv = bo[col];
#pragma unroll
        for (int i = 0; i < 4; i++)
#pragma unroll
            for (int r = 0; r < 4; r++) {
                const int row = m0 + wm * 64 + i * 16 + g * 4 + r;
                out[(size_t)row * ND + col] = acc[i][j][r] + bsv;
            }
    }
}

// ---------------------------------------------------------------------------
extern "C" void kernel_launch(void* const* d_in, const int* in_sizes, int n_in,
                              void* d_out, int out_size, void* d_ws, size_t ws_size,
                              hipStream_t stream) {
    const float* x  = (const float*)d_in[0];
    const float* Wq = (const float*)d_in[1];
    const float* bq = (const float*)d_in[2];
    const float* Wk = (const float*)d_in[3];
    const float* bk = (const float*)d_in[4];
    const float* Wv = (const float*)d_in[5];
    const float* bv = (const float*)d_in[6];
    const float* Wo = (const float*)d_in[7];
    const float* bo = (const float*)d_in[8];
    float* out = (float*)d_out;

    // ws layout (bf16 shorts): q, k, v^T, ctx, xb, wqb, wkb, wvb, wob = 50.3 MB
    const size_t qk_elems = (size_t)NB * NH * NS * NDH;   // 4,194,304
    const size_t w_elems  = (size_t)ND * ND;              // 1,048,576
    unsigned short* qbuf   = (unsigned short*)d_ws;
    unsigned short* kbuf   = qbuf + qk_elems;
    unsigned short* vtbuf  = kbuf + qk_elems;
    unsigned short* ctxbuf = vtbuf + qk_elems;
    unsigned short* xb     = ctxbuf + qk_elems;
    unsigned short* wqb    = xb + qk_elems;
    unsigned short* wkb    = wqb + w_elems;
    unsigned short* wvb    = wkb + w_elems;
    unsigned short* wob    = wvb + w_elems;

    cvt_kernel<<<4096, 256, 0, stream>>>(x, Wq, Wk, Wv, Wo, xb, wqb, wkb, wvb, wob);
    qkv_kernel<<<dim3(24, 32), 256, 0, stream>>>(xb, wqb, wkb, wvb, bq, bk, bv,
                                                 qbuf, kbuf, vtbuf);
    attn_kernel<<<dim3(16, 32), 512, 0, stream>>>(qbuf, kbuf, vtbuf, ctxbuf);
    out_kernel<<<dim3(8, 32), 256, 0, stream>>>(ctxbuf, wob, bo, out);
}